// Round 3
// baseline (1524.212 us; speedup 1.0000x reference)
//
#include <hip/hip_runtime.h>

typedef unsigned short u16;
typedef __bf16 bf16x8 __attribute__((ext_vector_type(8)));
typedef float f32x4 __attribute__((ext_vector_type(4)));

static __device__ __forceinline__ f32x4 mfma16(bf16x8 a, bf16x8 b, f32x4 c) {
  return __builtin_amdgcn_mfma_f32_16x16x32_bf16(a, b, c, 0, 0, 0);
}

static __device__ __forceinline__ u16 f2bf(float f) {
  union { float f; unsigned u; } v; v.f = f;
  unsigned r = v.u + 0x7fffu + ((v.u >> 16) & 1u);
  return (u16)(r >> 16);
}

// ---------------- mask element-size probe ----------------
__global__ void k_flag(const unsigned char* __restrict__ m, int* flag) {
  int t = threadIdx.x;  // 64 threads
  unsigned v = (unsigned)m[4*t+1] | (unsigned)m[4*t+2] | (unsigned)m[4*t+3];
  unsigned long long any = __ballot(v != 0);
  if (t == 0) *flag = (any == 0ull) ? 1 : 0;
}

// ---------------- mask bit-pack: elem -> 1 bit ----------------
__global__ __launch_bounds__(256) void k_pack(const void* __restrict__ m,
                                              const int* __restrict__ flagp,
                                              unsigned* __restrict__ out) {
  int flag = *flagp;
  int lane = threadIdx.x & 63;
  long elem = (long)blockIdx.x * 256 + (threadIdx.x >> 6) * 64 + lane;
  bool pred = flag ? (((const int*)m)[elem] != 0)
                   : (((const unsigned char*)m)[elem] != 0);
  unsigned long long bal = __ballot(pred);
  if (lane == 0)  out[elem >> 5] = (unsigned)bal;
  if (lane == 32) out[elem >> 5] = (unsigned)(bal >> 32);
}

// ---------------- weight transpose+convert: W[d][e] -> Wt[e][d] bf16 ----------------
__global__ __launch_bounds__(256) void k_wtr(const float* __restrict__ Wq,
                                             const float* __restrict__ Wk,
                                             const float* __restrict__ Wv,
                                             u16* __restrict__ Wt) {
  int m = blockIdx.z;
  const float* src = (m < 12) ? (Wq + (size_t)m * 65536)
                   : (m < 24) ? (Wk + (size_t)(m - 12) * 65536)
                              : (Wv + (size_t)(m - 24) * 65536);
  u16* dst = Wt + (size_t)m * 65536;
  __shared__ float T[64][65];
  int t = threadIdx.x;
  int d0 = blockIdx.x * 64, e0 = blockIdx.y * 64;
  for (int it = 0; it < 16; ++it) {
    int idx = it * 256 + t; int r = idx >> 6, c = idx & 63;
    T[r][c] = src[(size_t)(d0 + r) * 256 + e0 + c];
  }
  __syncthreads();
  for (int it = 0; it < 16; ++it) {
    int idx = it * 256 + t; int r = idx >> 6, c = idx & 63;
    dst[(size_t)(e0 + r) * 256 + d0 + c] = f2bf(T[c][r]);
  }
}

// ---------------- fp32 -> bf16 convert (+ optional fp32 copy) ----------------
__global__ __launch_bounds__(256) void k_cvt(const float* __restrict__ src,
                                             u16* __restrict__ db,
                                             float* dstf, long n) {
  long i = ((long)blockIdx.x * 256 + threadIdx.x) * 4;
  if (i >= n) return;
  float4 v = *(const float4*)(src + i);
  union { u16 u[4]; uint2 q; } o;
  o.u[0] = f2bf(v.x); o.u[1] = f2bf(v.y); o.u[2] = f2bf(v.z); o.u[3] = f2bf(v.w);
  *(uint2*)(db + i) = o.q;
  if (dstf) *(float4*)(dstf + i) = v;
}

// ---------------- fused 3-linear chain, register-prefetched W staging ----------------
template<int MODE>
__global__ __launch_bounds__(256, 2) void k_gemm3(const u16* __restrict__ X,
                                                  const u16* __restrict__ Wt,
                                                  const float* __restrict__ bias,
                                                  u16* __restrict__ out, int Nk) {
  __shared__ __align__(16) u16 Xs[64][264];
  __shared__ __align__(16) u16 Ws[256][40];
  int t = threadIdx.x, lane = t & 63, w = t >> 6, g = lane >> 4, li = lane & 15;
  long row0 = (long)blockIdx.x * 64;

  for (int it = 0; it < 8; ++it) {
    int c = it * 256 + t, r = c >> 5, k8 = (c & 31) << 3;
    *(uint4*)&Xs[r][k8] = *(const uint4*)&X[(row0 + r) * 256 + k8];
  }

  // prefetch W chunk (j=0, kk=0)
  uint4 pw[4];
  {
    const u16* p0 = Wt;  // + kk*32 with kk=0
#pragma unroll
    for (int it = 0; it < 4; ++it) {
      int c = it * 256 + t, n = c >> 2, p = c & 3;
      pw[it] = *(const uint4*)&p0[n * 256 + (p << 3)];
    }
  }

  for (int j = 0; j < 3; ++j) {
    f32x4 acc[4][4];
#pragma unroll
    for (int i = 0; i < 4; ++i)
#pragma unroll
      for (int jj = 0; jj < 4; ++jj) acc[i][jj] = (f32x4){0.f, 0.f, 0.f, 0.f};
    for (int kk = 0; kk < 8; ++kk) {
      __syncthreads();   // previous tile's LDS reads complete
#pragma unroll
      for (int it = 0; it < 4; ++it) {
        int c = it * 256 + t, n = c >> 2, p = c & 3;
        *(uint4*)&Ws[n][p << 3] = pw[it];
      }
      __syncthreads();   // staging visible
      // prefetch next chunk (possibly next j's chunk 0)
      {
        int nj = (kk < 7) ? j : j + 1, nkk = (kk < 7) ? kk + 1 : 0;
        if (nj < 3) {
          const u16* pn = Wt + nj * 65536 + nkk * 32;
#pragma unroll
          for (int it = 0; it < 4; ++it) {
            int c = it * 256 + t, n = c >> 2, p = c & 3;
            pw[it] = *(const uint4*)&pn[n * 256 + (p << 3)];
          }
        }
      }
      bf16x8 xf[4], wf[4];
#pragma unroll
      for (int f = 0; f < 4; ++f) xf[f] = *(const bf16x8*)&Xs[f * 16 + li][kk * 32 + g * 8];
#pragma unroll
      for (int f = 0; f < 4; ++f) wf[f] = *(const bf16x8*)&Ws[w * 64 + f * 16 + li][g * 8];
#pragma unroll
      for (int i = 0; i < 4; ++i)
#pragma unroll
        for (int jj = 0; jj < 4; ++jj)
          acc[i][jj] = (MODE == 0) ? mfma16(xf[i], wf[jj], acc[i][jj])
                                   : mfma16(wf[i], xf[jj], acc[i][jj]);
    }
    __syncthreads();   // all frag reads of Xs done before rewrite
    if (j < 2) {
#pragma unroll
      for (int i = 0; i < 4; ++i)
#pragma unroll
        for (int jj = 0; jj < 4; ++jj)
#pragma unroll
          for (int r = 0; r < 4; ++r) {
            int R, C;
            if (MODE == 0) { R = i * 16 + g * 4 + r; C = w * 64 + jj * 16 + li; }
            else           { R = jj * 16 + li;       C = w * 64 + i * 16 + g * 4 + r; }
            Xs[R][C] = f2bf(acc[i][jj][r] + bias[j * 256 + C]);
          }
    } else {
      if (MODE == 0) {
#pragma unroll
        for (int i = 0; i < 4; ++i)
#pragma unroll
          for (int jj = 0; jj < 4; ++jj)
#pragma unroll
            for (int r = 0; r < 4; ++r) {
              int R = i * 16 + g * 4 + r, C = w * 64 + jj * 16 + li;
              out[(row0 + R) * 256 + C] = f2bf(acc[i][jj][r] + bias[512 + C]);
            }
      } else {
        long b = row0 / Nk, rb = row0 - b * Nk;
#pragma unroll
        for (int i = 0; i < 4; ++i)
#pragma unroll
          for (int jj = 0; jj < 4; ++jj)
#pragma unroll
            for (int r = 0; r < 4; ++r) {
              int e = w * 64 + i * 16 + g * 4 + r, xr = jj * 16 + li;
              out[(b * 256 + e) * (long)Nk + rb + xr] = f2bf(acc[i][jj][r] + bias[512 + e]);
            }
      }
    }
  }
}

// ---------------- flash attention, k-split partials, register-prefetched ----------------
// Block = 64 q-rows x half the k-range. Wave w owns q rows [w*16, w*16+16),
// full k-tile, full d: P round-trip is wave-private (no barrier).
// Writes partial O-sums and l-sums; k_mrg combines + LayerNorm.
__global__ __launch_bounds__(256, 2) void k_attn(
    const u16* __restrict__ Qb, const u16* __restrict__ Kb, const u16* __restrict__ Vt,
    const unsigned* __restrict__ Mb,
    float* __restrict__ Opart, float* __restrict__ Lpart, int Nk) {
  __shared__ __align__(16) u16 Qs[64][264];
  __shared__ __align__(16) u16 Ks[32][264];
  __shared__ __align__(16) u16 Vs[256][40];
  __shared__ __align__(16) u16 Ps[4][16][40];
  __shared__ unsigned MskW[64];

  int t = threadIdx.x, lane = t & 63, w = t >> 6, g = lane >> 4, li = lane & 15;
  int bid = blockIdx.x;
  int s = bid & 1, qt = (bid >> 1) & 15, b = bid >> 5;
  int q0 = qt << 6;
  int ks0 = s * (Nk >> 1);
  int W = Nk >> 5;           // mask words per q-row
  int iters = Nk >> 6;       // (Nk/2)/32

  const u16* Qbase = Qb + ((long)b * 1024 + q0) * 256;
#pragma unroll
  for (int it = 0; it < 8; ++it) {
    int idx = it * 256 + t, r = idx >> 5, c = (idx & 31) << 3;
    *(uint4*)&Qs[r][c] = *(const uint4*)&Qbase[(long)r * 256 + c];
  }

  const u16* Kb0 = Kb + ((long)b * Nk + ks0) * 256;
  const u16* Vb0 = Vt + (long)b * 256 * (long)Nk + ks0;
  const unsigned* Mb0 = Mb + ((long)b * 1024 + q0) * W + (ks0 >> 5);

  f32x4 O[16];
#pragma unroll
  for (int i = 0; i < 16; ++i) O[i] = (f32x4){0.f, 0.f, 0.f, 0.f};
  float l_l[4] = {0.f, 0.f, 0.f, 0.f};

  // prologue prefetch (tile 0)
  uint4 pk[4], pv[4]; unsigned pm = 0;
#pragma unroll
  for (int it = 0; it < 4; ++it) {
    int r = it * 8 + (t >> 5), c = (t & 31) << 3;
    pk[it] = *(const uint4*)&Kb0[(long)r * 256 + c];
  }
#pragma unroll
  for (int it = 0; it < 4; ++it) {
    int idx = it * 256 + t, d = idx >> 2, p = (idx & 3) << 3;
    pv[it] = *(const uint4*)&Vb0[(long)d * Nk + p];
  }
  if (t < 64) pm = Mb0[(long)t * W];

  for (int ki = 0; ki < iters; ++ki) {
    __syncthreads();   // previous tile's LDS reads complete
#pragma unroll
    for (int it = 0; it < 4; ++it) {
      int r = it * 8 + (t >> 5), c = (t & 31) << 3;
      *(uint4*)&Ks[r][c] = pk[it];
    }
#pragma unroll
    for (int it = 0; it < 4; ++it) {
      int idx = it * 256 + t, d = idx >> 2, p = (idx & 3) << 3;
      *(uint4*)&Vs[d][p] = pv[it];
    }
    if (t < 64) MskW[t] = pm;
    __syncthreads();   // staging visible
    // prefetch next tile
    if (ki + 1 < iters) {
      int kb = (ki + 1) << 5;
#pragma unroll
      for (int it = 0; it < 4; ++it) {
        int r = it * 8 + (t >> 5), c = (t & 31) << 3;
        pk[it] = *(const uint4*)&Kb0[(long)(kb + r) * 256 + c];
      }
#pragma unroll
      for (int it = 0; it < 4; ++it) {
        int idx = it * 256 + t, d = idx >> 2, p = (idx & 3) << 3;
        pv[it] = *(const uint4*)&Vb0[(long)d * Nk + kb + p];
      }
      if (t < 64) pm = Mb0[(long)t * W + (kb >> 5)];
    }

    // QK^T: wave w computes S[16q x 32k] in two halves
    f32x4 s0 = (f32x4){0.f, 0.f, 0.f, 0.f}, s1 = (f32x4){0.f, 0.f, 0.f, 0.f};
#pragma unroll
    for (int kc = 0; kc < 8; ++kc) {
      bf16x8 a  = *(const bf16x8*)&Qs[w * 16 + li][kc * 32 + g * 8];
      bf16x8 k0 = *(const bf16x8*)&Ks[li][kc * 32 + g * 8];
      bf16x8 k1 = *(const bf16x8*)&Ks[16 + li][kc * 32 + g * 8];
      s0 = mfma16(a, k0, s0);
      s1 = mfma16(a, k1, s1);
    }
    // exp (no max), per-lane l accumulation, P -> wave-private LDS
#pragma unroll
    for (int r = 0; r < 4; ++r) {
      int qr = g * 4 + r;
      unsigned mw = MskW[w * 16 + qr];
      float e0 = (mw & (1u << li))        ? 0.f : __expf(s0[r] * 0.0625f);
      float e1 = (mw & (1u << (16 + li))) ? 0.f : __expf(s1[r] * 0.0625f);
      l_l[r] += e0 + e1;
      Ps[w][qr][li]      = f2bf(e0);
      Ps[w][qr][16 + li] = f2bf(e1);
    }
    // PV: wave-private read of P (lgkmcnt dependency only, no barrier)
    bf16x8 pa = *(const bf16x8*)&Ps[w][li][g * 8];
#pragma unroll
    for (int df = 0; df < 16; ++df) {
      bf16x8 bv = *(const bf16x8*)&Vs[df * 16 + li][g * 8];
      O[df] = mfma16(pa, bv, O[df]);
    }
  }

  // ---- epilogue: write partial l and O ----
  long pbase = ((long)s * 16384 + (long)b * 1024 + q0);
#pragma unroll
  for (int r = 0; r < 4; ++r) {
    float sv = l_l[r];
    sv += __shfl_xor(sv, 1); sv += __shfl_xor(sv, 2);
    sv += __shfl_xor(sv, 4); sv += __shfl_xor(sv, 8);
    if (li == 0) Lpart[pbase + w * 16 + g * 4 + r] = sv;
  }
#pragma unroll
  for (int df = 0; df < 16; ++df)
#pragma unroll
    for (int r = 0; r < 4; ++r)
      Opart[(pbase + w * 16 + g * 4 + r) * 256 + df * 16 + li] = O[df][r];
}

// ---------------- merge partials + LayerNorm + residual ----------------
__global__ __launch_bounds__(256) void k_mrg(
    const float* __restrict__ Opart, const float* __restrict__ Lpart,
    const float* __restrict__ gamma, const float* __restrict__ beta,
    float* xres, u16* xbout,
    const float* __restrict__ future, float* __restrict__ dout, int last) {
  int w = threadIdx.x >> 6, lane = threadIdx.x & 63;
  long row = (long)blockIdx.x * 4 + w;   // [0, 16384)
  int d = lane * 4;
  float4 a = *(const float4*)&Opart[row * 256 + d];
  float4 c = *(const float4*)&Opart[16384L * 256 + row * 256 + d];
  float rl = 1.f / fmaxf(Lpart[row] + Lpart[16384 + row], 1e-30f);
  float y0 = (a.x + c.x) * rl, y1 = (a.y + c.y) * rl;
  float y2 = (a.z + c.z) * rl, y3 = (a.w + c.w) * rl;
  float sm = y0 + y1 + y2 + y3;
  float s2 = y0 * y0 + y1 * y1 + y2 * y2 + y3 * y3;
#pragma unroll
  for (int o = 1; o < 64; o <<= 1) { sm += __shfl_xor(sm, o); s2 += __shfl_xor(s2, o); }
  float mu = sm * (1.f / 256.f);
  float rstd = rsqrtf(s2 * (1.f / 256.f) - mu * mu + 1e-5f);
  float4 gm = *(const float4*)&gamma[d];
  float4 bt = *(const float4*)&beta[d];
  float4 xr = *(const float4*)&xres[row * 256 + d];
  float o0 = (y0 - mu) * rstd * gm.x + bt.x + xr.x;
  float o1 = (y1 - mu) * rstd * gm.y + bt.y + xr.y;
  float o2 = (y2 - mu) * rstd * gm.z + bt.z + xr.z;
  float o3 = (y3 - mu) * rstd * gm.w + bt.w + xr.w;
  if (last) {
    float4 fu = *(const float4*)&future[row * 256 + d];
    float4 ov = {o0 + fu.x, o1 + fu.y, o2 + fu.z, o3 + fu.w};
    *(float4*)&dout[row * 256 + d] = ov;
  } else {
    float4 ov = {o0, o1, o2, o3};
    *(float4*)&xres[row * 256 + d] = ov;
    union { u16 u[4]; uint2 q; } p;
    p.u[0] = f2bf(o0); p.u[1] = f2bf(o1); p.u[2] = f2bf(o2); p.u[3] = f2bf(o3);
    *(uint2*)&xbout[row * 256 + d] = p.q;
  }
}

// ---------------- host ----------------
extern "C" void kernel_launch(void* const* d_in, const int* in_sizes, int n_in,
                              void* d_out, int out_size, void* d_ws, size_t ws_size,
                              hipStream_t stream) {
  const float* future  = (const float*)d_in[0];
  const float* history = (const float*)d_in[1];
  const float* graph   = (const float*)d_in[2];
  const void*  mask_hf = d_in[3];
  const void*  mask_fg = d_in[4];
  const float* Wq = (const float*)d_in[5];
  const float* bq = (const float*)d_in[6];
  const float* Wk = (const float*)d_in[7];
  const float* bk = (const float*)d_in[8];
  const float* Wv = (const float*)d_in[9];
  const float* bv = (const float*)d_in[10];
  const float* gamma = (const float*)d_in[11];
  const float* beta  = (const float*)d_in[12];
  float* dout = (float*)d_out;

  char* ws = (char*)d_ws;
  size_t off = 0;
  int* flag = (int*)(ws + off); off += 256;
  u16* Wt = (u16*)(ws + off);  off += (size_t)36 * 65536 * 2;
  u16* xb = (u16*)(ws + off);  off += (size_t)16384 * 256 * 2;
  float* x = (float*)(ws + off); off += (size_t)16384 * 256 * 4;
  u16* hb = (u16*)(ws + off);  off += (size_t)16384 * 256 * 2;
  u16* gb = (u16*)(ws + off);  off += (size_t)32768 * 256 * 2;
  u16* Qb = (u16*)(ws + off);  off += (size_t)16384 * 256 * 2;
  u16* Kb = (u16*)(ws + off);  off += (size_t)32768 * 256 * 2;
  u16* Vtb = (u16*)(ws + off); off += (size_t)32768 * 256 * 2;
  unsigned* Mbhf = (unsigned*)(ws + off); off += (size_t)16 * 1024 * 1024 / 8;
  unsigned* Mbfg = (unsigned*)(ws + off); off += (size_t)16 * 1024 * 2048 / 8;
  float* Opart = (float*)(ws + off); off += (size_t)2 * 16384 * 256 * 4;
  float* Lpart = (float*)(ws + off); off += (size_t)2 * 16384 * 4;
  if (ws_size < off) return;

  u16* WtQ = Wt;
  u16* WtK = Wt + (size_t)12 * 65536;
  u16* WtV = Wt + (size_t)24 * 65536;

  k_flag<<<1, 64, 0, stream>>>((const unsigned char*)mask_hf, flag);
  k_pack<<<65536, 256, 0, stream>>>(mask_hf, flag, Mbhf);
  k_pack<<<131072, 256, 0, stream>>>(mask_fg, flag, Mbfg);
  k_wtr<<<dim3(4, 4, 36), 256, 0, stream>>>(Wq, Wk, Wv, Wt);
  k_cvt<<<4096, 256, 0, stream>>>(future, xb, x, 4194304L);
  k_cvt<<<4096, 256, 0, stream>>>(history, hb, nullptr, 4194304L);
  k_cvt<<<8192, 256, 0, stream>>>(graph, gb, nullptr, 8388608L);

  for (int i = 0; i < 4; ++i) {
    const u16* src = (i < 2) ? hb : gb;
    int M2 = (i < 2) ? 16384 : 32768;
    int Nk = (i < 2) ? 1024 : 2048;
    const unsigned* mb = (i < 2) ? Mbhf : Mbfg;
    k_gemm3<0><<<256, 256, 0, stream>>>(xb, WtQ + (size_t)i * 3 * 65536, bq + i * 768, Qb, 0);
    k_gemm3<0><<<M2 / 64, 256, 0, stream>>>(src, WtK + (size_t)i * 3 * 65536, bk + i * 768, Kb, 0);
    k_gemm3<1><<<M2 / 64, 256, 0, stream>>>(src, WtV + (size_t)i * 3 * 65536, bv + i * 768, Vtb, Nk);
    k_attn<<<512, 256, 0, stream>>>(Qb, Kb, Vtb, mb, Opart, Lpart, Nk);
    k_mrg<<<4096, 256, 0, stream>>>(Opart, Lpart, gamma + i * 256, beta + i * 256,
                                    x, xb, future, dout, (i == 3) ? 1 : 0);
  }
}

// Round 4
// 1243.280 us; speedup vs baseline: 1.2260x; 1.2260x over previous
//
#include <hip/hip_runtime.h>

typedef unsigned short u16;
typedef __bf16 bf16x8 __attribute__((ext_vector_type(8)));
typedef float f32x4 __attribute__((ext_vector_type(4)));

static __device__ __forceinline__ f32x4 mfma16(bf16x8 a, bf16x8 b, f32x4 c) {
  return __builtin_amdgcn_mfma_f32_16x16x32_bf16(a, b, c, 0, 0, 0);
}

static __device__ __forceinline__ u16 f2bf(float f) {
  union { float f; unsigned u; } v; v.f = f;
  unsigned r = v.u + 0x7fffu + ((v.u >> 16) & 1u);
  return (u16)(r >> 16);
}

// ---------------- mask element-size probe ----------------
__global__ void k_flag(const unsigned char* __restrict__ m, int* flag) {
  int t = threadIdx.x;  // 64 threads
  unsigned v = (unsigned)m[4*t+1] | (unsigned)m[4*t+2] | (unsigned)m[4*t+3];
  unsigned long long any = __ballot(v != 0);
  if (t == 0) *flag = (any == 0ull) ? 1 : 0;
}

// ---------------- mask bit-pack: elem -> 1 bit (8 waves-worth per block) ----------------
__global__ __launch_bounds__(256) void k_pack(const void* __restrict__ m,
                                              const int* __restrict__ flagp,
                                              unsigned* __restrict__ out) {
  int flag = *flagp;
  int lane = threadIdx.x & 63, wv = threadIdx.x >> 6;
  long base = (long)blockIdx.x * 2048 + wv * 64 + lane;
#pragma unroll
  for (int it = 0; it < 8; ++it) {
    long elem = base + it * 256;
    bool pred = flag ? (((const int*)m)[elem] != 0)
                     : (((const unsigned char*)m)[elem] != 0);
    unsigned long long bal = __ballot(pred);
    if (lane == 0)  out[elem >> 5] = (unsigned)bal;
    if (lane == 32) out[elem >> 5] = (unsigned)(bal >> 32);
  }
}

// ---------------- weight transpose+convert: W[d][e] -> Wt[e][d] bf16 ----------------
__global__ __launch_bounds__(256) void k_wtr(const float* __restrict__ Wq,
                                             const float* __restrict__ Wk,
                                             const float* __restrict__ Wv,
                                             u16* __restrict__ Wt) {
  int m = blockIdx.z;
  const float* src = (m < 12) ? (Wq + (size_t)m * 65536)
                   : (m < 24) ? (Wk + (size_t)(m - 12) * 65536)
                              : (Wv + (size_t)(m - 24) * 65536);
  u16* dst = Wt + (size_t)m * 65536;
  __shared__ float T[64][65];
  int t = threadIdx.x;
  int d0 = blockIdx.x * 64, e0 = blockIdx.y * 64;
  for (int it = 0; it < 16; ++it) {
    int idx = it * 256 + t; int r = idx >> 6, c = idx & 63;
    T[r][c] = src[(size_t)(d0 + r) * 256 + e0 + c];
  }
  __syncthreads();
  for (int it = 0; it < 16; ++it) {
    int idx = it * 256 + t; int r = idx >> 6, c = idx & 63;
    dst[(size_t)(e0 + r) * 256 + d0 + c] = f2bf(T[c][r]);
  }
}

// ---------------- fp32 -> bf16 convert (+ optional fp32 copy) ----------------
__global__ __launch_bounds__(256) void k_cvt(const float* __restrict__ src,
                                             u16* __restrict__ db,
                                             float* dstf, long n) {
  long i = ((long)blockIdx.x * 256 + threadIdx.x) * 4;
  if (i >= n) return;
  float4 v = *(const float4*)(src + i);
  union { u16 u[4]; uint2 q; } o;
  o.u[0] = f2bf(v.x); o.u[1] = f2bf(v.y); o.u[2] = f2bf(v.z); o.u[3] = f2bf(v.w);
  *(uint2*)(db + i) = o.q;
  if (dstf) *(float4*)(dstf + i) = v;
}

// ---------------- fused 3-linear chain (R2 version, known-good) ----------------
template<int MODE>
__global__ __launch_bounds__(256, 2) void k_gemm3(const u16* __restrict__ X,
                                                  const u16* __restrict__ Wt,
                                                  const float* __restrict__ bias,
                                                  u16* __restrict__ out, int Nk) {
  __shared__ __align__(16) u16 Xs[64][264];
  __shared__ __align__(16) u16 Ws[256][40];
  int t = threadIdx.x, lane = t & 63, w = t >> 6, g = lane >> 4, li = lane & 15;
  long row0 = (long)blockIdx.x * 64;

  for (int it = 0; it < 8; ++it) {
    int c = it * 256 + t, r = c >> 5, k8 = (c & 31) << 3;
    *(uint4*)&Xs[r][k8] = *(const uint4*)&X[(row0 + r) * 256 + k8];
  }

  for (int j = 0; j < 3; ++j) {
    f32x4 acc[4][4];
#pragma unroll
    for (int i = 0; i < 4; ++i)
#pragma unroll
      for (int jj = 0; jj < 4; ++jj) acc[i][jj] = (f32x4){0.f, 0.f, 0.f, 0.f};
    const u16* Wj = Wt + j * 65536;
    for (int kk = 0; kk < 8; ++kk) {
#pragma unroll
      for (int it = 0; it < 4; ++it) {
        int c = it * 256 + t, n = c >> 2, p = c & 3;
        *(uint4*)&Ws[n][p << 3] = *(const uint4*)&Wj[n * 256 + kk * 32 + (p << 3)];
      }
      __syncthreads();
      bf16x8 xf[4], wf[4];
#pragma unroll
      for (int f = 0; f < 4; ++f) xf[f] = *(const bf16x8*)&Xs[f * 16 + li][kk * 32 + g * 8];
#pragma unroll
      for (int f = 0; f < 4; ++f) wf[f] = *(const bf16x8*)&Ws[w * 64 + f * 16 + li][g * 8];
#pragma unroll
      for (int i = 0; i < 4; ++i)
#pragma unroll
        for (int jj = 0; jj < 4; ++jj)
          acc[i][jj] = (MODE == 0) ? mfma16(xf[i], wf[jj], acc[i][jj])
                                   : mfma16(wf[i], xf[jj], acc[i][jj]);
      __syncthreads();
    }
    if (j < 2) {
#pragma unroll
      for (int i = 0; i < 4; ++i)
#pragma unroll
        for (int jj = 0; jj < 4; ++jj)
#pragma unroll
          for (int r = 0; r < 4; ++r) {
            int R, C;
            if (MODE == 0) { R = i * 16 + g * 4 + r; C = w * 64 + jj * 16 + li; }
            else           { R = jj * 16 + li;       C = w * 64 + i * 16 + g * 4 + r; }
            Xs[R][C] = f2bf(acc[i][jj][r] + bias[j * 256 + C]);
          }
      __syncthreads();
    } else {
      if (MODE == 0) {
#pragma unroll
        for (int i = 0; i < 4; ++i)
#pragma unroll
          for (int jj = 0; jj < 4; ++jj)
#pragma unroll
            for (int r = 0; r < 4; ++r) {
              int R = i * 16 + g * 4 + r, C = w * 64 + jj * 16 + li;
              out[(row0 + R) * 256 + C] = f2bf(acc[i][jj][r] + bias[512 + C]);
            }
      } else {
        long b = row0 / Nk, rb = row0 - b * Nk;
#pragma unroll
        for (int i = 0; i < 4; ++i)
#pragma unroll
          for (int jj = 0; jj < 4; ++jj)
#pragma unroll
            for (int r = 0; r < 4; ++r) {
              int e = w * 64 + i * 16 + g * 4 + r, xr = jj * 16 + li;
              out[(b * 256 + e) * (long)Nk + rb + xr] = f2bf(acc[i][jj][r] + bias[512 + e]);
            }
      }
    }
  }
}

// ---------------- flash attention: Q-in-registers, 2x fragment reuse ----------------
// Block = 64 q-rows, full Nk. Wave (qg,h): owns q [qg*32, qg*32+32).
// QK: S[32q x 16k] (k-half h). PV: O[32q x 128d] (d-half h) over full 32k.
// Q fragments live in VGPRs for the whole kernel (zero Q LDS reads in-loop).
// K/V LDS double-buffered (buffer 1 aliases the Q staging area).
__global__ __launch_bounds__(256, 2) void k_attn(
    const u16* __restrict__ Qb, const u16* __restrict__ Kb, const u16* __restrict__ Vt,
    const unsigned* __restrict__ Mb,
    const float* __restrict__ gamma, const float* __restrict__ beta,
    float* xres, u16* xbout,
    const float* __restrict__ future, float* __restrict__ dout, int last, int Nk) {
  // KV buf: [0..8447] = K 32x264, [8448..18687] = V 256x40
  __shared__ __align__(16) u16 KV[2][18688];
  __shared__ __align__(16) u16 Ps[2][32][40];
  __shared__ unsigned MskW[2][64];
  __shared__ float Lred[2][2][32], Sred[2][2][32], Qred[2][2][32];

  int t = threadIdx.x, lane = t & 63, w = t >> 6;
  int qg = w >> 1, h = w & 1, g = lane >> 4, li = lane & 15;
  int b = blockIdx.x >> 4, q0 = (blockIdx.x & 15) << 6;
  int W = Nk >> 5, iters = Nk >> 5;

  const u16* Qg = Qb + ((long)b * 1024 + q0) * 256;
  const u16* Kg = Kb + (long)b * Nk * 256;
  const u16* Vg = Vt + (long)b * 256 * (long)Nk;
  const unsigned* Mg = Mb + ((long)b * 1024 + q0) * (long)W;

  // stage Q into KV[1] (64x264 view)
  u16 (*Qs)[264] = (u16(*)[264])&KV[1][0];
  {
    uint4 tq[8];
#pragma unroll
    for (int it = 0; it < 8; ++it) {
      int idx = it * 256 + t, r = idx >> 5, c = (idx & 31) << 3;
      tq[it] = *(const uint4*)&Qg[(long)r * 256 + c];
    }
#pragma unroll
    for (int it = 0; it < 8; ++it) {
      int idx = it * 256 + t, r = idx >> 5, c = (idx & 31) << 3;
      *(uint4*)&Qs[r][c] = tq[it];
    }
  }

  uint4 pk[4], pv[4]; unsigned pm = 0;
#define PREF(n_) do { long kb_ = (long)(n_) << 5;                                  \
    _Pragma("unroll")                                                              \
    for (int it = 0; it < 4; ++it) { int idx = it * 256 + t;                       \
      int r_ = idx >> 5, c_ = (idx & 31) << 3;                                     \
      pk[it] = *(const uint4*)&Kg[(kb_ + r_) * 256 + c_]; }                        \
    _Pragma("unroll")                                                              \
    for (int it = 0; it < 4; ++it) { int idx = it * 256 + t;                       \
      int d_ = idx >> 2, p_ = (idx & 3) << 3;                                      \
      pv[it] = *(const uint4*)&Vg[(long)d_ * Nk + kb_ + p_]; }                     \
    if (t < 64) pm = Mg[(long)t * W + (n_)]; } while (0)
#define STAGE(buf_) do {                                                           \
    u16 (*Ks_)[264] = (u16(*)[264])&KV[buf_][0];                                   \
    u16 (*Vs_)[40] = (u16(*)[40])&KV[buf_][8448];                                  \
    _Pragma("unroll")                                                              \
    for (int it = 0; it < 4; ++it) { int idx = it * 256 + t;                       \
      int r_ = idx >> 5, c_ = (idx & 31) << 3;                                     \
      *(uint4*)&Ks_[r_][c_] = pk[it]; }                                            \
    _Pragma("unroll")                                                              \
    for (int it = 0; it < 4; ++it) { int idx = it * 256 + t;                       \
      int d_ = idx >> 2, p_ = (idx & 3) << 3;                                      \
      *(uint4*)&Vs_[d_][p_] = pv[it]; }                                            \
    if (t < 64) MskW[buf_][t] = pm; } while (0)

  PREF(0);
  STAGE(0);          // tile 0 into buf 0 (K/V area disjoint from... buf0 != Qs) 
  __syncthreads();   // Q + tile0 visible

  // Q fragments -> registers (16 x bf16x8 = 64 VGPR), wave-private
  bf16x8 qf[2][8];
#pragma unroll
  for (int i = 0; i < 2; ++i)
#pragma unroll
    for (int kc = 0; kc < 8; ++kc)
      qf[i][kc] = *(const bf16x8*)&Qs[qg * 32 + i * 16 + li][kc * 32 + g * 8];

  PREF(1);           // tile 1 into regs (staged into KV[1]=Qs area at iter 0)

  f32x4 O[2][8];
#pragma unroll
  for (int i = 0; i < 2; ++i)
#pragma unroll
    for (int df = 0; df < 8; ++df) O[i][df] = (f32x4){0.f, 0.f, 0.f, 0.f};
  float l_l[2][4] = {{0.f, 0.f, 0.f, 0.f}, {0.f, 0.f, 0.f, 0.f}};

  for (int ki = 0; ki < iters; ++ki) {
    int cb = ki & 1, sb = cb ^ 1;
    __syncthreads();   // staged tile ki visible; prior-iter reads of KV[sb] done
    if (ki + 1 < iters) {
      STAGE(sb);
      if (ki + 2 < iters) PREF(ki + 2);
    }
    u16 (*Ks)[264] = (u16(*)[264])&KV[cb][0];
    u16 (*Vs)[40] = (u16(*)[40])&KV[cb][8448];

    // QK^T: 16 MFMA from 8 Ks reads (each feeds both q-subtiles)
    f32x4 s0 = (f32x4){0.f, 0.f, 0.f, 0.f}, s1 = (f32x4){0.f, 0.f, 0.f, 0.f};
#pragma unroll
    for (int kc = 0; kc < 8; ++kc) {
      bf16x8 kf = *(const bf16x8*)&Ks[h * 16 + li][kc * 32 + g * 8];
      s0 = mfma16(qf[0][kc], kf, s0);
      s1 = mfma16(qf[1][kc], kf, s1);
    }
    // exp (no max), P -> LDS (wave's k-half), per-lane l accumulation
#pragma unroll
    for (int i = 0; i < 2; ++i) {
      f32x4 sv = i ? s1 : s0;
#pragma unroll
      for (int r = 0; r < 4; ++r) {
        int qr = i * 16 + g * 4 + r;
        unsigned mw = MskW[cb][qg * 32 + qr];
        bool km = (mw >> (h * 16 + li)) & 1u;
        float e = km ? 0.f : __expf(sv[r] * 0.0625f);
        l_l[i][r] += e;
        Ps[qg][qr][h * 16 + li] = f2bf(e);
      }
    }
    __syncthreads();   // both k-halves of P visible
    // PV: 16 MFMA from 8 Vs reads + 2 Ps reads
    bf16x8 pa0 = *(const bf16x8*)&Ps[qg][li][g * 8];
    bf16x8 pa1 = *(const bf16x8*)&Ps[qg][16 + li][g * 8];
#pragma unroll
    for (int df = 0; df < 8; ++df) {
      bf16x8 bv = *(const bf16x8*)&Vs[h * 128 + df * 16 + li][g * 8];
      O[0][df] = mfma16(pa0, bv, O[0][df]);
      O[1][df] = mfma16(pa1, bv, O[1][df]);
    }
  }
#undef PREF
#undef STAGE

  // ---- epilogue: l reduce (li + cross-h), y=O/l, LayerNorm, +residual ----
#pragma unroll
  for (int i = 0; i < 2; ++i)
#pragma unroll
    for (int r = 0; r < 4; ++r) {
      float sv = l_l[i][r];
      sv += __shfl_xor(sv, 1); sv += __shfl_xor(sv, 2);
      sv += __shfl_xor(sv, 4); sv += __shfl_xor(sv, 8);
      if (li == 0) Lred[h][qg][i * 16 + g * 4 + r] = sv;
    }
  __syncthreads();
  float rl[2][4];
#pragma unroll
  for (int i = 0; i < 2; ++i)
#pragma unroll
    for (int r = 0; r < 4; ++r) {
      int qr = i * 16 + g * 4 + r;
      rl[i][r] = 1.f / fmaxf(Lred[0][qg][qr] + Lred[1][qg][qr], 1e-30f);
    }
#pragma unroll
  for (int i = 0; i < 2; ++i)
#pragma unroll
    for (int df = 0; df < 8; ++df)
#pragma unroll
      for (int r = 0; r < 4; ++r) O[i][df][r] *= rl[i][r];

#pragma unroll
  for (int i = 0; i < 2; ++i)
#pragma unroll
    for (int r = 0; r < 4; ++r) {
      float sm = 0.f, s2 = 0.f;
#pragma unroll
      for (int df = 0; df < 8; ++df) { float y = O[i][df][r]; sm += y; s2 += y * y; }
      sm += __shfl_xor(sm, 1); sm += __shfl_xor(sm, 2);
      sm += __shfl_xor(sm, 4); sm += __shfl_xor(sm, 8);
      s2 += __shfl_xor(s2, 1); s2 += __shfl_xor(s2, 2);
      s2 += __shfl_xor(s2, 4); s2 += __shfl_xor(s2, 8);
      if (li == 0) {
        Sred[h][qg][i * 16 + g * 4 + r] = sm;
        Qred[h][qg][i * 16 + g * 4 + r] = s2;
      }
    }
  __syncthreads();
  float mu_[2][4], rstd[2][4];
#pragma unroll
  for (int i = 0; i < 2; ++i)
#pragma unroll
    for (int r = 0; r < 4; ++r) {
      int qr = i * 16 + g * 4 + r;
      float S = Sred[0][qg][qr] + Sred[1][qg][qr];
      float Q2 = Qred[0][qg][qr] + Qred[1][qg][qr];
      float m = S * (1.f / 256.f);
      mu_[i][r] = m;
      rstd[i][r] = rsqrtf(Q2 * (1.f / 256.f) - m * m + 1e-5f);
    }
#pragma unroll
  for (int i = 0; i < 2; ++i)
#pragma unroll
    for (int df = 0; df < 8; ++df) {
      int d = h * 128 + df * 16 + li;
      float gm = gamma[d], bt = beta[d];
#pragma unroll
      for (int r = 0; r < 4; ++r) {
        int q = q0 + qg * 32 + i * 16 + g * 4 + r;
        long idx = ((long)b * 1024 + q) * 256 + d;
        float o = (O[i][df][r] - mu_[i][r]) * rstd[i][r] * gm + bt + xres[idx];
        if (last) dout[idx] = o + future[idx];
        else { xres[idx] = o; xbout[idx] = f2bf(o); }
      }
    }
}

// ---------------- host ----------------
extern "C" void kernel_launch(void* const* d_in, const int* in_sizes, int n_in,
                              void* d_out, int out_size, void* d_ws, size_t ws_size,
                              hipStream_t stream) {
  const float* future  = (const float*)d_in[0];
  const float* history = (const float*)d_in[1];
  const float* graph   = (const float*)d_in[2];
  const void*  mask_hf = d_in[3];
  const void*  mask_fg = d_in[4];
  const float* Wq = (const float*)d_in[5];
  const float* bq = (const float*)d_in[6];
  const float* Wk = (const float*)d_in[7];
  const float* bk = (const float*)d_in[8];
  const float* Wv = (const float*)d_in[9];
  const float* bv = (const float*)d_in[10];
  const float* gamma = (const float*)d_in[11];
  const float* beta  = (const float*)d_in[12];
  float* dout = (float*)d_out;

  char* ws = (char*)d_ws;
  size_t off = 0;
  int* flag = (int*)(ws + off); off += 256;
  u16* Wt = (u16*)(ws + off);  off += (size_t)36 * 65536 * 2;
  u16* xb = (u16*)(ws + off);  off += (size_t)16384 * 256 * 2;
  float* x = (float*)(ws + off); off += (size_t)16384 * 256 * 4;
  u16* hb = (u16*)(ws + off);  off += (size_t)16384 * 256 * 2;
  u16* gb = (u16*)(ws + off);  off += (size_t)32768 * 256 * 2;
  u16* Qb = (u16*)(ws + off);  off += (size_t)16384 * 256 * 2;
  u16* Kb = (u16*)(ws + off);  off += (size_t)32768 * 256 * 2;
  u16* Vtb = (u16*)(ws + off); off += (size_t)32768 * 256 * 2;
  unsigned* Mbhf = (unsigned*)(ws + off); off += (size_t)16 * 1024 * 1024 / 8;
  unsigned* Mbfg = (unsigned*)(ws + off); off += (size_t)16 * 1024 * 2048 / 8;
  if (ws_size < off) return;

  u16* WtQ = Wt;
  u16* WtK = Wt + (size_t)12 * 65536;
  u16* WtV = Wt + (size_t)24 * 65536;

  k_flag<<<1, 64, 0, stream>>>((const unsigned char*)mask_hf, flag);
  k_pack<<<8192, 256, 0, stream>>>(mask_hf, flag, Mbhf);
  k_pack<<<16384, 256, 0, stream>>>(mask_fg, flag, Mbfg);
  k_wtr<<<dim3(4, 4, 36), 256, 0, stream>>>(Wq, Wk, Wv, Wt);
  k_cvt<<<4096, 256, 0, stream>>>(future, xb, x, 4194304L);
  k_cvt<<<4096, 256, 0, stream>>>(history, hb, nullptr, 4194304L);
  k_cvt<<<8192, 256, 0, stream>>>(graph, gb, nullptr, 8388608L);

  for (int i = 0; i < 4; ++i) {
    const u16* src = (i < 2) ? hb : gb;
    int M2 = (i < 2) ? 16384 : 32768;
    int Nk = (i < 2) ? 1024 : 2048;
    const unsigned* mb = (i < 2) ? Mbhf : Mbfg;
    k_gemm3<0><<<256, 256, 0, stream>>>(xb, WtQ + (size_t)i * 3 * 65536, bq + i * 768, Qb, 0);
    k_gemm3<0><<<M2 / 64, 256, 0, stream>>>(src, WtK + (size_t)i * 3 * 65536, bk + i * 768, Kb, 0);
    k_gemm3<1><<<M2 / 64, 256, 0, stream>>>(src, WtV + (size_t)i * 3 * 65536, bv + i * 768, Vtb, Nk);
    k_attn<<<256, 256, 0, stream>>>(Qb, Kb, Vtb, mb, gamma + i * 256, beta + i * 256,
                                    x, xb, future, dout, (i == 3) ? 1 : 0, Nk);
  }
}

// Round 5
// 954.338 us; speedup vs baseline: 1.5971x; 1.3028x over previous
//
#include <hip/hip_runtime.h>

typedef unsigned short u16;
typedef __bf16 bf16x8 __attribute__((ext_vector_type(8)));
typedef float f32x4 __attribute__((ext_vector_type(4)));

static __device__ __forceinline__ f32x4 mfma16(bf16x8 a, bf16x8 b, f32x4 c) {
  return __builtin_amdgcn_mfma_f32_16x16x32_bf16(a, b, c, 0, 0, 0);
}

static __device__ __forceinline__ u16 f2bf(float f) {
  union { float f; unsigned u; } v; v.f = f;
  unsigned r = v.u + 0x7fffu + ((v.u >> 16) & 1u);
  return (u16)(r >> 16);
}

// ---------------- mask element-size probe ----------------
__global__ void k_flag(const unsigned char* __restrict__ m, int* flag) {
  int t = threadIdx.x;  // 64 threads
  unsigned v = (unsigned)m[4*t+1] | (unsigned)m[4*t+2] | (unsigned)m[4*t+3];
  unsigned long long any = __ballot(v != 0);
  if (t == 0) *flag = (any == 0ull) ? 1 : 0;
}

// ---------------- mask bit-pack: elem -> 1 bit ----------------
__global__ __launch_bounds__(256) void k_pack(const void* __restrict__ m,
                                              const int* __restrict__ flagp,
                                              unsigned* __restrict__ out) {
  int flag = *flagp;
  int lane = threadIdx.x & 63, wv = threadIdx.x >> 6;
  long base = (long)blockIdx.x * 2048 + wv * 64 + lane;
#pragma unroll
  for (int it = 0; it < 8; ++it) {
    long elem = base + it * 256;
    bool pred = flag ? (((const int*)m)[elem] != 0)
                     : (((const unsigned char*)m)[elem] != 0);
    unsigned long long bal = __ballot(pred);
    if (lane == 0)  out[elem >> 5] = (unsigned)bal;
    if (lane == 32) out[elem >> 5] = (unsigned)(bal >> 32);
  }
}

// ---------------- weight transpose+convert: W[d][e] -> Wt[e][d] bf16 ----------------
__global__ __launch_bounds__(256) void k_wtr(const float* __restrict__ Wq,
                                             const float* __restrict__ Wk,
                                             const float* __restrict__ Wv,
                                             u16* __restrict__ Wt) {
  int m = blockIdx.z;
  const float* src = (m < 12) ? (Wq + (size_t)m * 65536)
                   : (m < 24) ? (Wk + (size_t)(m - 12) * 65536)
                              : (Wv + (size_t)(m - 24) * 65536);
  u16* dst = Wt + (size_t)m * 65536;
  __shared__ float T[64][65];
  int t = threadIdx.x;
  int d0 = blockIdx.x * 64, e0 = blockIdx.y * 64;
  for (int it = 0; it < 16; ++it) {
    int idx = it * 256 + t; int r = idx >> 6, c = idx & 63;
    T[r][c] = src[(size_t)(d0 + r) * 256 + e0 + c];
  }
  __syncthreads();
  for (int it = 0; it < 16; ++it) {
    int idx = it * 256 + t; int r = idx >> 6, c = idx & 63;
    dst[(size_t)(e0 + r) * 256 + d0 + c] = f2bf(T[c][r]);
  }
}

// ---------------- fp32 -> bf16 convert (+ optional fp32 copy) ----------------
__global__ __launch_bounds__(256) void k_cvt(const float* __restrict__ src,
                                             u16* __restrict__ db,
                                             float* dstf, long n) {
  long i = ((long)blockIdx.x * 256 + threadIdx.x) * 4;
  if (i >= n) return;
  float4 v = *(const float4*)(src + i);
  union { u16 u[4]; uint2 q; } o;
  o.u[0] = f2bf(v.x); o.u[1] = f2bf(v.y); o.u[2] = f2bf(v.z); o.u[3] = f2bf(v.w);
  *(uint2*)(db + i) = o.q;
  if (dstf) *(float4*)(dstf + i) = v;
}

// ---------------- fused 3-linear chain (R2 version, known-good) ----------------
template<int MODE>
__global__ __launch_bounds__(256, 2) void k_gemm3(const u16* __restrict__ X,
                                                  const u16* __restrict__ Wt,
                                                  const float* __restrict__ bias,
                                                  u16* __restrict__ out, int Nk) {
  __shared__ __align__(16) u16 Xs[64][264];
  __shared__ __align__(16) u16 Ws[256][40];
  int t = threadIdx.x, lane = t & 63, w = t >> 6, g = lane >> 4, li = lane & 15;
  long row0 = (long)blockIdx.x * 64;

  for (int it = 0; it < 8; ++it) {
    int c = it * 256 + t, r = c >> 5, k8 = (c & 31) << 3;
    *(uint4*)&Xs[r][k8] = *(const uint4*)&X[(row0 + r) * 256 + k8];
  }

  for (int j = 0; j < 3; ++j) {
    f32x4 acc[4][4];
#pragma unroll
    for (int i = 0; i < 4; ++i)
#pragma unroll
      for (int jj = 0; jj < 4; ++jj) acc[i][jj] = (f32x4){0.f, 0.f, 0.f, 0.f};
    const u16* Wj = Wt + j * 65536;
    for (int kk = 0; kk < 8; ++kk) {
#pragma unroll
      for (int it = 0; it < 4; ++it) {
        int c = it * 256 + t, n = c >> 2, p = c & 3;
        *(uint4*)&Ws[n][p << 3] = *(const uint4*)&Wj[n * 256 + kk * 32 + (p << 3)];
      }
      __syncthreads();
      bf16x8 xf[4], wf[4];
#pragma unroll
      for (int f = 0; f < 4; ++f) xf[f] = *(const bf16x8*)&Xs[f * 16 + li][kk * 32 + g * 8];
#pragma unroll
      for (int f = 0; f < 4; ++f) wf[f] = *(const bf16x8*)&Ws[w * 64 + f * 16 + li][g * 8];
#pragma unroll
      for (int i = 0; i < 4; ++i)
#pragma unroll
        for (int jj = 0; jj < 4; ++jj)
          acc[i][jj] = (MODE == 0) ? mfma16(xf[i], wf[jj], acc[i][jj])
                                   : mfma16(wf[i], xf[jj], acc[i][jj]);
      __syncthreads();
    }
    if (j < 2) {
#pragma unroll
      for (int i = 0; i < 4; ++i)
#pragma unroll
        for (int jj = 0; jj < 4; ++jj)
#pragma unroll
          for (int r = 0; r < 4; ++r) {
            int R, C;
            if (MODE == 0) { R = i * 16 + g * 4 + r; C = w * 64 + jj * 16 + li; }
            else           { R = jj * 16 + li;       C = w * 64 + i * 16 + g * 4 + r; }
            Xs[R][C] = f2bf(acc[i][jj][r] + bias[j * 256 + C]);
          }
      __syncthreads();
    } else {
      if (MODE == 0) {
#pragma unroll
        for (int i = 0; i < 4; ++i)
#pragma unroll
          for (int jj = 0; jj < 4; ++jj)
#pragma unroll
            for (int r = 0; r < 4; ++r) {
              int R = i * 16 + g * 4 + r, C = w * 64 + jj * 16 + li;
              out[(row0 + R) * 256 + C] = f2bf(acc[i][jj][r] + bias[512 + C]);
            }
      } else {
        long b = row0 / Nk, rb = row0 - b * Nk;
#pragma unroll
        for (int i = 0; i < 4; ++i)
#pragma unroll
          for (int jj = 0; jj < 4; ++jj)
#pragma unroll
            for (int r = 0; r < 4; ++r) {
              int e = w * 64 + i * 16 + g * 4 + r, xr = jj * 16 + li;
              out[(b * 256 + e) * (long)Nk + rb + xr] = f2bf(acc[i][jj][r] + bias[512 + e]);
            }
      }
    }
  }
}

// ---------------- flash attention: 512-thr block, Q-in-regs, in-block k-split ----------------
// Block = 64 q-rows, 8 waves: w -> (qg = w>>2, h = (w>>1)&1, s = w&1).
// s-group stages its own K/V half; wave computes S[32q x 16k(h)] of half s,
// then O[32q x 128d(h)] partial over half s. Epilogue merges s-partials in LDS.
__global__ __launch_bounds__(512, 2) void k_attn(
    const u16* __restrict__ Qb, const u16* __restrict__ Kb, const u16* __restrict__ Vt,
    const unsigned* __restrict__ Mb,
    const float* __restrict__ gamma, const float* __restrict__ beta,
    float* xres, u16* xbout,
    const float* __restrict__ future, float* __restrict__ dout, int last, int Nk) {
  __shared__ __align__(16) char RAW[85504];
  u16 (*Qs)[264]        = (u16(*)[264])RAW;                    // [64][264]  (prologue)
  u16 (*KsA)[32][264]   = (u16(*)[32][264])RAW;                // [2][32][264] (loop)
  u16 (*VsA)[256][40]   = (u16(*)[256][40])(RAW + 33792);      // [2][256][40]
  u16 (*PsA)[2][32][40] = (u16(*)[2][32][40])(RAW + 74752);    // [s][qg][32][40]
  unsigned (*MskA)[64]  = (unsigned(*)[64])(RAW + 84992);      // [2][64]
  float* LredP = (float*)(RAW + 74752);          // [s*4+h*2+qg][32] (aliases Ps, epilogue)
  float* SredP = (float*)(RAW + 74752 + 2048);   // [h*2+qg][32]
  float* QredP = (float*)(RAW + 74752 + 4096);   // [h*2+qg][32]
  float* mrgF  = (float*)RAW;                    // [128][132] (aliases Qs/Ks/Vs, epilogue)

  int t = threadIdx.x, lane = t & 63, w = t >> 6;
  int qg = w >> 2, h = (w >> 1) & 1, s = w & 1;
  int g = lane >> 4, li = lane & 15;
  int gl = (w >> 1) * 64 + lane;   // 0..255, unique within s-group
  int b = blockIdx.x >> 4, q0 = (blockIdx.x & 15) << 6;
  int W = Nk >> 5, iters = Nk >> 6, soff = s * (Nk >> 1);

  const u16* Qg = Qb + ((long)b * 1024 + q0) * 256;
  const u16* Kg = Kb + ((long)b * Nk + soff) * 256;
  const u16* Vg = Vt + (long)b * 256 * (long)Nk + soff;
  const unsigned* Mg = Mb + ((long)b * 1024 + q0) * (long)W + s * (Nk >> 6);

  // ---- prologue: stage Q, load Q fragments to registers ----
#pragma unroll
  for (int it = 0; it < 4; ++it) {
    int idx = it * 512 + t, r = idx >> 5, c = (idx & 31) << 3;
    *(uint4*)&Qs[r][c] = *(const uint4*)&Qg[(long)r * 256 + c];
  }
  __syncthreads();
  bf16x8 qf[2][8];
#pragma unroll
  for (int i = 0; i < 2; ++i)
#pragma unroll
    for (int kc = 0; kc < 8; ++kc)
      qf[i][kc] = *(const bf16x8*)&Qs[qg * 32 + i * 16 + li][kc * 32 + g * 8];

  f32x4 O[2][8];
#pragma unroll
  for (int i = 0; i < 2; ++i)
#pragma unroll
    for (int df = 0; df < 8; ++df) O[i][df] = (f32x4){0.f, 0.f, 0.f, 0.f};
  float l_l[2][4] = {{0.f, 0.f, 0.f, 0.f}, {0.f, 0.f, 0.f, 0.f}};

  for (int ki = 0; ki < iters; ++ki) {
    int kb = ki << 5;
    __syncthreads();   // prev tile reads (or qf loads) complete
#pragma unroll
    for (int it = 0; it < 4; ++it) {
      int idx = it * 256 + gl, r = idx >> 5, c = (idx & 31) << 3;
      *(uint4*)&KsA[s][r][c] = *(const uint4*)&Kg[(long)(kb + r) * 256 + c];
    }
#pragma unroll
    for (int it = 0; it < 4; ++it) {
      int idx = it * 256 + gl, d = idx >> 2, p = (idx & 3) << 3;
      *(uint4*)&VsA[s][d][p] = *(const uint4*)&Vg[(long)d * Nk + kb + p];
    }
    if (gl < 64) MskA[s][gl] = Mg[(long)gl * W + ki];
    __syncthreads();   // staging visible

    // QK^T: S[32q x 16k], k-half h of split s; 16 MFMA from 8 K reads
    f32x4 s0 = (f32x4){0.f, 0.f, 0.f, 0.f}, s1 = (f32x4){0.f, 0.f, 0.f, 0.f};
#pragma unroll
    for (int kc = 0; kc < 8; ++kc) {
      bf16x8 kf = *(const bf16x8*)&KsA[s][h * 16 + li][kc * 32 + g * 8];
      s0 = mfma16(qf[0][kc], kf, s0);
      s1 = mfma16(qf[1][kc], kf, s1);
    }
#pragma unroll
    for (int i = 0; i < 2; ++i) {
      f32x4 sv = i ? s1 : s0;
#pragma unroll
      for (int r = 0; r < 4; ++r) {
        int qr = i * 16 + g * 4 + r;
        unsigned mw = MskA[s][qg * 32 + qr];
        bool km = (mw >> (h * 16 + li)) & 1u;
        float e = km ? 0.f : __expf(sv[r] * 0.0625f);
        l_l[i][r] += e;
        PsA[s][qg][qr][h * 16 + li] = f2bf(e);
      }
    }
    __syncthreads();   // both h-halves of P visible
    // PV: O[32q x 128d(h)] over this 32-k tile; 16 MFMA from 8 V + 2 P reads
    bf16x8 pa0 = *(const bf16x8*)&PsA[s][qg][li][g * 8];
    bf16x8 pa1 = *(const bf16x8*)&PsA[s][qg][16 + li][g * 8];
#pragma unroll
    for (int df = 0; df < 8; ++df) {
      bf16x8 bv = *(const bf16x8*)&VsA[s][h * 128 + df * 16 + li][g * 8];
      O[0][df] = mfma16(pa0, bv, O[0][df]);
      O[1][df] = mfma16(pa1, bv, O[1][df]);
    }
  }

  // ---- epilogue: merge s-partials in LDS, LayerNorm, +residual ----
  __syncthreads();   // B1: loop LDS reads done (Ps/Ks/Vs areas free)
#pragma unroll
  for (int i = 0; i < 2; ++i)
#pragma unroll
    for (int r = 0; r < 4; ++r) {
      float sv = l_l[i][r];
      sv += __shfl_xor(sv, 1); sv += __shfl_xor(sv, 2);
      sv += __shfl_xor(sv, 4); sv += __shfl_xor(sv, 8);
      if (li == 0) LredP[(s * 4 + h * 2 + qg) * 32 + i * 16 + g * 4 + r] = sv;
    }
  if (s == 1) {
#pragma unroll
    for (int i = 0; i < 2; ++i)
#pragma unroll
      for (int df = 0; df < 8; ++df)
#pragma unroll
        for (int r = 0; r < 4; ++r) {
          int mr = (qg * 2 + h) * 32 + i * 16 + g * 4 + r;
          mrgF[mr * 132 + df * 16 + li] = O[i][df][r];
        }
  }
  __syncthreads();   // B2
  if (s == 0) {
    float rl[2][4];
#pragma unroll
    for (int i = 0; i < 2; ++i)
#pragma unroll
      for (int r = 0; r < 4; ++r) {
        int qr = i * 16 + g * 4 + r;
        float lt = LredP[(qg) * 32 + qr] + LredP[(2 + qg) * 32 + qr]
                 + LredP[(4 + qg) * 32 + qr] + LredP[(6 + qg) * 32 + qr];
        rl[i][r] = 1.f / fmaxf(lt, 1e-30f);
      }
    float sm[2][4] = {{0.f,0.f,0.f,0.f},{0.f,0.f,0.f,0.f}};
    float s2[2][4] = {{0.f,0.f,0.f,0.f},{0.f,0.f,0.f,0.f}};
#pragma unroll
    for (int i = 0; i < 2; ++i)
#pragma unroll
      for (int df = 0; df < 8; ++df)
#pragma unroll
        for (int r = 0; r < 4; ++r) {
          int mr = (qg * 2 + h) * 32 + i * 16 + g * 4 + r;
          float y = (O[i][df][r] + mrgF[mr * 132 + df * 16 + li]) * rl[i][r];
          O[i][df][r] = y;
          sm[i][r] += y; s2[i][r] += y * y;
        }
#pragma unroll
    for (int i = 0; i < 2; ++i)
#pragma unroll
      for (int r = 0; r < 4; ++r) {
        float a = sm[i][r], c = s2[i][r];
        a += __shfl_xor(a, 1); a += __shfl_xor(a, 2);
        a += __shfl_xor(a, 4); a += __shfl_xor(a, 8);
        c += __shfl_xor(c, 1); c += __shfl_xor(c, 2);
        c += __shfl_xor(c, 4); c += __shfl_xor(c, 8);
        if (li == 0) {
          SredP[(h * 2 + qg) * 32 + i * 16 + g * 4 + r] = a;
          QredP[(h * 2 + qg) * 32 + i * 16 + g * 4 + r] = c;
        }
      }
  }
  __syncthreads();   // B3
  if (s == 0) {
    float mu_[2][4], rstd[2][4];
#pragma unroll
    for (int i = 0; i < 2; ++i)
#pragma unroll
      for (int r = 0; r < 4; ++r) {
        int qr = i * 16 + g * 4 + r;
        float S = SredP[(qg) * 32 + qr] + SredP[(2 + qg) * 32 + qr];
        float Q2 = QredP[(qg) * 32 + qr] + QredP[(2 + qg) * 32 + qr];
        float m = S * (1.f / 256.f);
        mu_[i][r] = m;
        rstd[i][r] = rsqrtf(Q2 * (1.f / 256.f) - m * m + 1e-5f);
      }
#pragma unroll
    for (int i = 0; i < 2; ++i)
#pragma unroll
      for (int df = 0; df < 8; ++df) {
        int d = h * 128 + df * 16 + li;
        float gm = gamma[d], bt = beta[d];
#pragma unroll
        for (int r = 0; r < 4; ++r) {
          int q = q0 + qg * 32 + i * 16 + g * 4 + r;
          long idx = ((long)b * 1024 + q) * 256 + d;
          float o = (O[i][df][r] - mu_[i][r]) * rstd[i][r] * gm + bt + xres[idx];
          if (last) dout[idx] = o + future[idx];
          else { xres[idx] = o; xbout[idx] = f2bf(o); }
        }
      }
  }
}

// ---------------- host ----------------
extern "C" void kernel_launch(void* const* d_in, const int* in_sizes, int n_in,
                              void* d_out, int out_size, void* d_ws, size_t ws_size,
                              hipStream_t stream) {
  const float* future  = (const float*)d_in[0];
  const float* history = (const float*)d_in[1];
  const float* graph   = (const float*)d_in[2];
  const void*  mask_hf = d_in[3];
  const void*  mask_fg = d_in[4];
  const float* Wq = (const float*)d_in[5];
  const float* bq = (const float*)d_in[6];
  const float* Wk = (const float*)d_in[7];
  const float* bk = (const float*)d_in[8];
  const float* Wv = (const float*)d_in[9];
  const float* bv = (const float*)d_in[10];
  const float* gamma = (const float*)d_in[11];
  const float* beta  = (const float*)d_in[12];
  float* dout = (float*)d_out;

  char* ws = (char*)d_ws;
  size_t off = 0;
  int* flag = (int*)(ws + off); off += 256;
  u16* Wt = (u16*)(ws + off);  off += (size_t)36 * 65536 * 2;
  u16* xb = (u16*)(ws + off);  off += (size_t)16384 * 256 * 2;
  float* x = (float*)(ws + off); off += (size_t)16384 * 256 * 4;
  u16* hb = (u16*)(ws + off);  off += (size_t)16384 * 256 * 2;
  u16* gb = (u16*)(ws + off);  off += (size_t)32768 * 256 * 2;
  u16* Qb = (u16*)(ws + off);  off += (size_t)16384 * 256 * 2;
  u16* Kb = (u16*)(ws + off);  off += (size_t)32768 * 256 * 2;
  u16* Vtb = (u16*)(ws + off); off += (size_t)32768 * 256 * 2;
  unsigned* Mbhf = (unsigned*)(ws + off); off += (size_t)16 * 1024 * 1024 / 8;
  unsigned* Mbfg = (unsigned*)(ws + off); off += (size_t)16 * 1024 * 2048 / 8;
  if (ws_size < off) return;

  u16* WtQ = Wt;
  u16* WtK = Wt + (size_t)12 * 65536;
  u16* WtV = Wt + (size_t)24 * 65536;

  k_flag<<<1, 64, 0, stream>>>((const unsigned char*)mask_hf, flag);
  k_pack<<<8192, 256, 0, stream>>>(mask_hf, flag, Mbhf);
  k_pack<<<16384, 256, 0, stream>>>(mask_fg, flag, Mbfg);
  k_wtr<<<dim3(4, 4, 36), 256, 0, stream>>>(Wq, Wk, Wv, Wt);
  k_cvt<<<4096, 256, 0, stream>>>(future, xb, x, 4194304L);
  k_cvt<<<4096, 256, 0, stream>>>(history, hb, nullptr, 4194304L);
  k_cvt<<<8192, 256, 0, stream>>>(graph, gb, nullptr, 8388608L);

  for (int i = 0; i < 4; ++i) {
    const u16* src = (i < 2) ? hb : gb;
    int M2 = (i < 2) ? 16384 : 32768;
    int Nk = (i < 2) ? 1024 : 2048;
    const unsigned* mb = (i < 2) ? Mbhf : Mbfg;
    k_gemm3<0><<<256, 256, 0, stream>>>(xb, WtQ + (size_t)i * 3 * 65536, bq + i * 768, Qb, 0);
    k_gemm3<0><<<M2 / 64, 256, 0, stream>>>(src, WtK + (size_t)i * 3 * 65536, bk + i * 768, Kb, 0);
    k_gemm3<1><<<M2 / 64, 256, 0, stream>>>(src, WtV + (size_t)i * 3 * 65536, bv + i * 768, Vtb, Nk);
    k_attn<<<256, 512, 0, stream>>>(Qb, Kb, Vtb, mb, gamma + i * 256, beta + i * 256,
                                    x, xb, future, dout, (i == 3) ? 1 : 0, Nk);
  }
}